// Round 6
// baseline (446.600 us; speedup 1.0000x reference)
//
#include <hip/hip_runtime.h>
#include <stdint.h>

typedef float  f32x4  __attribute__((ext_vector_type(4)));
typedef __bf16 bf16x8 __attribute__((ext_vector_type(8)));

#define AS1 __attribute__((address_space(1)))
#define AS3 __attribute__((address_space(3)))

// Problem constants
// B=2, S=2048, HID=2048, NH=16, HD=128, RING=4, CH=512, DIL=2
// packed length per (b,h,parity) = 1024; packed kv-chunk = 256

// ---------------- convert x: f32 -> bf16, 4 elems/thread ----------------
__global__ void k_cvt_x(const float* __restrict__ x, __bf16* __restrict__ y) {
  const int i = blockIdx.x * 256 + threadIdx.x;
  const float4 v = reinterpret_cast<const float4*>(x)[i];
  union { __bf16 b[4]; uint64_t u; } o;
  o.b[0] = (__bf16)v.x; o.b[1] = (__bf16)v.y; o.b[2] = (__bf16)v.z; o.b[3] = (__bf16)v.w;
  reinterpret_cast<uint64_t*>(y)[i] = o.u;
}

// ------- transpose+convert W[K][N] f32 -> Wt[N][K] bf16 (64x64 tiles) -------
__global__ void k_cvt_wt(const float* __restrict__ w, __bf16* __restrict__ wt,
                         const int K, const int N) {
  __shared__ float tile[64][65];
  const int k0 = blockIdx.x * 64, n0 = blockIdx.y * 64;
  const int t = threadIdx.x;
  #pragma unroll
  for (int i = 0; i < 16; ++i) {
    const int idx = t + 256 * i;
    const int r = idx >> 6, c = idx & 63;
    tile[r][c] = w[(size_t)(k0 + r) * N + n0 + c];
  }
  __syncthreads();
  #pragma unroll
  for (int i = 0; i < 16; ++i) {
    const int idx = t + 256 * i;
    const int r = idx >> 6, c = idx & 63;
    wt[(size_t)(n0 + r) * K + k0 + c] = (__bf16)tile[c][r];
  }
}

// ---------------- bt-GEMM: C[M][N] = A[M][K] * Bt[N][K]^T (bf16 in, f32 acc)
// EPI==1: scatter epilogue into parity-packed Q,K (s-major) and V (d-major)
// EPI==2: plain f32 row-major output
template<int EPI>
__global__ __launch_bounds__(256, 2) void k_gemm_bt(
    const __bf16* __restrict__ A, const __bf16* __restrict__ Bt,
    __bf16* __restrict__ Oq, __bf16* __restrict__ Ok, __bf16* __restrict__ Ov,
    float* __restrict__ Of, const int M, const int N, const int K) {
  __shared__ __bf16 As[128 * 32];
  __shared__ __bf16 Bs[128 * 32];
  const int tid = threadIdx.x;
  const int w = tid >> 6, l = tid & 63, g = l >> 4, l15 = l & 15;
  const int wr = w >> 1, wc = w & 1;
  const int m0 = blockIdx.y * 128, n0 = blockIdx.x * 128;
  const int srow = l >> 2, scol = (l & 3) * 8;   // staging: lane -> (row%16, col)

  f32x4 acc[4][4] = {};

  for (int kt = 0; kt < K; kt += 32) {
    __syncthreads();
    #pragma unroll
    for (int i = 0; i < 2; ++i) {
      const int ch = w * 2 + i;              // 1KB chunk id (wave-uniform)
      const int row = ch * 16 + srow;
      __builtin_amdgcn_global_load_lds(
          (const AS1 uint32_t*)(A + (size_t)(m0 + row) * K + kt + scol),
          (AS3 uint32_t*)(As + ch * 512), 16, 0, 0);
      __builtin_amdgcn_global_load_lds(
          (const AS1 uint32_t*)(Bt + (size_t)(n0 + row) * K + kt + scol),
          (AS3 uint32_t*)(Bs + ch * 512), 16, 0, 0);
    }
    __syncthreads();

    bf16x8 af[4], bfr[4];
    #pragma unroll
    for (int mi = 0; mi < 4; ++mi)
      af[mi] = *reinterpret_cast<const bf16x8*>(As + (wr * 64 + mi * 16 + l15) * 32 + 8 * g);
    #pragma unroll
    for (int ni = 0; ni < 4; ++ni)
      bfr[ni] = *reinterpret_cast<const bf16x8*>(Bs + (wc * 64 + ni * 16 + l15) * 32 + 8 * g);
    #pragma unroll
    for (int mi = 0; mi < 4; ++mi)
      #pragma unroll
      for (int ni = 0; ni < 4; ++ni)
        acc[mi][ni] = __builtin_amdgcn_mfma_f32_16x16x32_bf16(af[mi], bfr[ni], acc[mi][ni], 0, 0, 0);
  }

  if constexpr (EPI == 1) {
    // n block (128-wide, aligned) lies inside exactly one (t, h)
    const int t = n0 >> 11;                 // 0:q 1:k 2:v
    const int h = (n0 & 2047) >> 7;
    const int bb = m0 >> 11;
    #pragma unroll
    for (int mi = 0; mi < 4; ++mi) {
      #pragma unroll
      for (int r = 0; r < 4; ++r) {
        const int m = m0 + wr * 64 + mi * 16 + 4 * g + r;
        const int s = m & 2047;
        const int sp = s & 1, s2 = s >> 1;
        const size_t base = ((((size_t)bb * 16 + h) * 2 + sp) << 17);  // *131072
        #pragma unroll
        for (int ni = 0; ni < 4; ++ni) {
          const int d = wc * 64 + ni * 16 + l15;
          const __bf16 v = (__bf16)acc[mi][ni][r];
          if (t == 0)      Oq[base + (size_t)s2 * 128 + d] = v;
          else if (t == 1) Ok[base + (size_t)s2 * 128 + d] = v;
          else             Ov[base + (size_t)d * 1024 + s2] = v;
        }
      }
    }
  } else {
    #pragma unroll
    for (int mi = 0; mi < 4; ++mi)
      #pragma unroll
      for (int ni = 0; ni < 4; ++ni)
        #pragma unroll
        for (int r = 0; r < 4; ++r) {
          const int m = m0 + wr * 64 + mi * 16 + 4 * g + r;
          const int n = n0 + wc * 64 + ni * 16 + l15;
          Of[(size_t)m * N + n] = acc[mi][ni][r];
        }
  }
}

// ---------------- fused dilated ring attention v3 (parity-packed) ----------------
// grid: 2048 blocks = (b2,h16,p2,qt32), XCD-chunked swizzle. 256 thr = 4 waves:
// wq = w>>1 (two 16-row q subtiles), wk = w&1 (contiguous 128-col kv half).
// Per wave: s[8] (32 regs) + num[8] (32 regs) -> accum = 64 exactly; no spill
// at (256,3). K and V read DIRECT from global (XCD-L2-resident).
// E is wave-private LDS (no barriers around PV). 1 barrier/chunk (max
// exchange, parity-double-buffered) + 2 at epilogue (num/den combine).
// NOTE: den[r] is a PER-LANE partial (this lane's l15 columns only) until the
// epilogue butterfly — round-5 bug was writing it to denbuf un-reduced.
__global__ __launch_bounds__(256, 3) void k_attn(
    const __bf16* __restrict__ Qp, const __bf16* __restrict__ Kp,
    const __bf16* __restrict__ Vt, __bf16* __restrict__ attn) {
  __shared__ __bf16 E[4][16][136];         // 17408 B, wave-private quarters (+8 pad)
  __shared__ float maxbuf[2][2][2][16];    // [c&1][wq][wk][qrow]
  __shared__ float denbuf[2][2][16];       // [wq][wk][qrow]
  float* numbuf = (float*)&E[0][0][0];     // end-of-kernel alias: [2][16][132] f32

  const int bx = blockIdx.x;
  const int wid = (bx & 7) * 256 + (bx >> 3);   // XCD-chunked (2048 % 8 == 0)
  const int qt = wid & 31, p = (wid >> 5) & 1, h = (wid >> 6) & 15, b = wid >> 10;
  const int tid = threadIdx.x;
  const int w = tid >> 6, l = tid & 63, g = l >> 4, l15 = l & 15;
  const int wq = w >> 1, wk = w & 1;
  const size_t base = ((((size_t)b * 16 + h) * 2 + p) << 17);  // *131072
  const __bf16* Qb = Qp + base;
  const __bf16* Kb = Kp + base;
  const __bf16* Vb = Vt + base;
  const int q0 = qt * 32 + wq * 16;
  const float SC = 1.4426950408889634f / 11.313708498984761f;  // log2(e)/sqrt(128)

  bf16x8 qf[4];
  #pragma unroll
  for (int ks = 0; ks < 4; ++ks)
    qf[ks] = *reinterpret_cast<const bf16x8*>(Qb + (size_t)(q0 + l15) * 128 + ks * 32 + 8 * g);

  f32x4 num[8] = {};
  float den[4] = {0.f, 0.f, 0.f, 0.f};

  for (int c = 0; c < 4; ++c) {
    const int kvb = c * 256 + wk * 128;    // this wave's contiguous kv half
    // ---- QK^T: 16q x 128kv, K direct from global (L2) ----
    f32x4 s[8] = {};
    #pragma unroll
    for (int nfl = 0; nfl < 8; ++nfl) {
      const __bf16* kr = Kb + (size_t)(kvb + nfl * 16 + l15) * 128 + 8 * g;
      #pragma unroll
      for (int ks = 0; ks < 4; ++ks) {
        const bf16x8 kf = *reinterpret_cast<const bf16x8*>(kr + ks * 32);
        s[nfl] = __builtin_amdgcn_mfma_f32_16x16x32_bf16(qf[ks], kf, s[nfl], 0, 0, 0);
      }
    }
    // ---- half-max (in-wave), then cross-pair max via LDS, 1 barrier ----
    float mv[4];
    #pragma unroll
    for (int r = 0; r < 4; ++r) {
      float m0v = s[0][r];
      #pragma unroll
      for (int nfl = 1; nfl < 8; ++nfl) m0v = fmaxf(m0v, s[nfl][r]);
      m0v = fmaxf(m0v, __shfl_xor(m0v, 1));
      m0v = fmaxf(m0v, __shfl_xor(m0v, 2));
      m0v = fmaxf(m0v, __shfl_xor(m0v, 4));
      m0v = fmaxf(m0v, __shfl_xor(m0v, 8));
      mv[r] = m0v;
    }
    if (l15 == 0) {
      #pragma unroll
      for (int r = 0; r < 4; ++r) maxbuf[c & 1][wq][wk][4 * g + r] = mv[r];
    }
    __syncthreads();
    // ---- exp with full-chunk max; per-lane partial den; E (wave-private) ----
    #pragma unroll
    for (int r = 0; r < 4; ++r) {
      const float M = fmaxf(mv[r], maxbuf[c & 1][wq][wk ^ 1][4 * g + r]);
      float ds = 0.f;
      #pragma unroll
      for (int nfl = 0; nfl < 8; ++nfl) {
        const float e = exp2f((s[nfl][r] - M) * SC);
        E[w][4 * g + r][nfl * 16 + l15] = (__bf16)e;
        ds += e;
      }
      den[r] += ds;   // per-lane partial; butterfly-reduced at epilogue
    }
    // ---- PV: num[16x128] += E(16x128) @ V'[128x128], V direct (L2) ----
    #pragma unroll
    for (int ks2 = 0; ks2 < 4; ++ks2) {
      const bf16x8 a = *reinterpret_cast<const bf16x8*>(&E[w][l15][ks2 * 32 + 8 * g]);
      #pragma unroll
      for (int nd = 0; nd < 8; ++nd) {
        const bf16x8 vf = *reinterpret_cast<const bf16x8*>(
            Vb + (size_t)(nd * 16 + l15) * 1024 + kvb + ks2 * 32 + 8 * g);
        num[nd] = __builtin_amdgcn_mfma_f32_16x16x32_bf16(a, vf, num[nd], 0, 0, 0);
      }
    }
  }

  // ---- cross-lane den reduction (deferred; linear in chunks) ----
  #pragma unroll
  for (int r = 0; r < 4; ++r) {
    den[r] += __shfl_xor(den[r], 1);
    den[r] += __shfl_xor(den[r], 2);
    den[r] += __shfl_xor(den[r], 4);
    den[r] += __shfl_xor(den[r], 8);
  }

  // ---- epilogue: combine wk pair (den scalar + num via LDS), wk==0 writes ----
  if (l15 == 0) {
    #pragma unroll
    for (int r = 0; r < 4; ++r) denbuf[wq][wk][4 * g + r] = den[r];
  }
  __syncthreads();                 // all PV E-reads done; denbuf visible
  if (wk == 1) {
    #pragma unroll
    for (int nd = 0; nd < 8; ++nd)
      #pragma unroll
      for (int r = 0; r < 4; ++r)
        numbuf[((size_t)wq * 16 + 4 * g + r) * 132 + nd * 16 + l15] = num[nd][r];
  }
  __syncthreads();
  if (wk == 0) {
    float dt[4];
    #pragma unroll
    for (int r = 0; r < 4; ++r) dt[r] = den[r] + denbuf[wq][1][4 * g + r] + 1e-8f;
    #pragma unroll
    for (int nd = 0; nd < 8; ++nd)
      #pragma unroll
      for (int r = 0; r < 4; ++r) {
        const float nt = num[nd][r] +
            numbuf[((size_t)wq * 16 + 4 * g + r) * 132 + nd * 16 + l15];
        const int sq = q0 + 4 * g + r;         // packed q index
        const int srow = 2 * sq + p;           // original sequence pos
        attn[((size_t)b * 2048 + srow) * 2048 + h * 128 + nd * 16 + l15] =
            (__bf16)(nt / dt[r]);
      }
  }
}

extern "C" void kernel_launch(void* const* d_in, const int* in_sizes, int n_in,
                              void* d_out, int out_size, void* d_ws, size_t ws_size,
                              hipStream_t stream) {
  (void)in_sizes; (void)n_in; (void)out_size; (void)ws_size;
  const float* x    = (const float*)d_in[0];
  const float* wqkv = (const float*)d_in[1];
  const float* wout = (const float*)d_in[2];
  float* out = (float*)d_out;
  uint8_t* ws = (uint8_t*)d_ws;

  // workspace layout (bytes); total needed = 96 MB
  __bf16* xbf   = (__bf16*)(ws + 0);                    // 16 MB [4096][2048]
  __bf16* wqkvt = (__bf16*)(ws + (16ull << 20));        // 24 MB [6144][2048]
  __bf16* woutt = (__bf16*)(ws + (40ull << 20));        //  8 MB [2048][2048]
  __bf16* Qp    = (__bf16*)(ws + (48ull << 20));        // 16 MB [b][h][p][1024][128]
  __bf16* Kp    = (__bf16*)(ws + (64ull << 20));        // 16 MB [b][h][p][1024][128]
  __bf16* Vt    = (__bf16*)(ws + (80ull << 20));        // 16 MB [b][h][p][128][1024]
  __bf16* attn  = (__bf16*)(ws + 0);                    // reuse xbf (dead after GEMM1)

  k_cvt_x<<<8192, 256, 0, stream>>>(x, xbf);
  k_cvt_wt<<<dim3(32, 96), 256, 0, stream>>>(wqkv, wqkvt, 2048, 6144);
  k_cvt_wt<<<dim3(32, 32), 256, 0, stream>>>(wout, woutt, 2048, 2048);
  // qkv projection, fused parity-pack + V-transpose epilogue
  k_gemm_bt<1><<<dim3(48, 32), 256, 0, stream>>>(xbf, wqkvt, Qp, Kp, Vt, nullptr, 4096, 6144, 2048);
  // fused dilated attention
  k_attn<<<2048, 256, 0, stream>>>(Qp, Kp, Vt, attn);
  // output projection -> f32
  k_gemm_bt<2><<<dim3(16, 32), 256, 0, stream>>>(attn, woutt, nullptr, nullptr, nullptr, out, 4096, 2048, 2048);
}

// Round 7
// 297.025 us; speedup vs baseline: 1.5036x; 1.5036x over previous
//
#include <hip/hip_runtime.h>
#include <stdint.h>

typedef float  f32x4  __attribute__((ext_vector_type(4)));
typedef __bf16 bf16x8 __attribute__((ext_vector_type(8)));

#define AS1 __attribute__((address_space(1)))
#define AS3 __attribute__((address_space(3)))

// Problem constants
// B=2, S=2048, HID=2048, NH=16, HD=128, RING=4, CH=512, DIL=2
// packed length per (b,h,parity) = 1024; packed kv-chunk = 256

// ---------------- convert x: f32 -> bf16, 4 elems/thread ----------------
__global__ void k_cvt_x(const float* __restrict__ x, __bf16* __restrict__ y) {
  const int i = blockIdx.x * 256 + threadIdx.x;
  const float4 v = reinterpret_cast<const float4*>(x)[i];
  union { __bf16 b[4]; uint64_t u; } o;
  o.b[0] = (__bf16)v.x; o.b[1] = (__bf16)v.y; o.b[2] = (__bf16)v.z; o.b[3] = (__bf16)v.w;
  reinterpret_cast<uint64_t*>(y)[i] = o.u;
}

// ------- transpose+convert W[K][N] f32 -> Wt[N][K] bf16 (64x64 tiles) -------
__global__ void k_cvt_wt(const float* __restrict__ w, __bf16* __restrict__ wt,
                         const int K, const int N) {
  __shared__ float tile[64][65];
  const int k0 = blockIdx.x * 64, n0 = blockIdx.y * 64;
  const int t = threadIdx.x;
  #pragma unroll
  for (int i = 0; i < 16; ++i) {
    const int idx = t + 256 * i;
    const int r = idx >> 6, c = idx & 63;
    tile[r][c] = w[(size_t)(k0 + r) * N + n0 + c];
  }
  __syncthreads();
  #pragma unroll
  for (int i = 0; i < 16; ++i) {
    const int idx = t + 256 * i;
    const int r = idx >> 6, c = idx & 63;
    wt[(size_t)(n0 + r) * K + k0 + c] = (__bf16)tile[c][r];
  }
}

// ---------------- bt-GEMM: C[M][N] = A[M][K] * Bt[N][K]^T (bf16 in, f32 acc)
// EPI==1: scatter epilogue into parity-packed Q,K (s-major) and V (d-major)
// EPI==2: plain f32 row-major output
template<int EPI>
__global__ __launch_bounds__(256, 2) void k_gemm_bt(
    const __bf16* __restrict__ A, const __bf16* __restrict__ Bt,
    __bf16* __restrict__ Oq, __bf16* __restrict__ Ok, __bf16* __restrict__ Ov,
    float* __restrict__ Of, const int M, const int N, const int K) {
  __shared__ __bf16 As[128 * 32];
  __shared__ __bf16 Bs[128 * 32];
  const int tid = threadIdx.x;
  const int w = tid >> 6, l = tid & 63, g = l >> 4, l15 = l & 15;
  const int wr = w >> 1, wc = w & 1;
  const int m0 = blockIdx.y * 128, n0 = blockIdx.x * 128;
  const int srow = l >> 2, scol = (l & 3) * 8;   // staging: lane -> (row%16, col)

  f32x4 acc[4][4] = {};

  for (int kt = 0; kt < K; kt += 32) {
    __syncthreads();
    #pragma unroll
    for (int i = 0; i < 2; ++i) {
      const int ch = w * 2 + i;              // 1KB chunk id (wave-uniform)
      const int row = ch * 16 + srow;
      __builtin_amdgcn_global_load_lds(
          (const AS1 uint32_t*)(A + (size_t)(m0 + row) * K + kt + scol),
          (AS3 uint32_t*)(As + ch * 512), 16, 0, 0);
      __builtin_amdgcn_global_load_lds(
          (const AS1 uint32_t*)(Bt + (size_t)(n0 + row) * K + kt + scol),
          (AS3 uint32_t*)(Bs + ch * 512), 16, 0, 0);
    }
    __syncthreads();

    bf16x8 af[4], bfr[4];
    #pragma unroll
    for (int mi = 0; mi < 4; ++mi)
      af[mi] = *reinterpret_cast<const bf16x8*>(As + (wr * 64 + mi * 16 + l15) * 32 + 8 * g);
    #pragma unroll
    for (int ni = 0; ni < 4; ++ni)
      bfr[ni] = *reinterpret_cast<const bf16x8*>(Bs + (wc * 64 + ni * 16 + l15) * 32 + 8 * g);
    #pragma unroll
    for (int mi = 0; mi < 4; ++mi)
      #pragma unroll
      for (int ni = 0; ni < 4; ++ni)
        acc[mi][ni] = __builtin_amdgcn_mfma_f32_16x16x32_bf16(af[mi], bfr[ni], acc[mi][ni], 0, 0, 0);
  }

  if constexpr (EPI == 1) {
    // n block (128-wide, aligned) lies inside exactly one (t, h)
    const int t = n0 >> 11;                 // 0:q 1:k 2:v
    const int h = (n0 & 2047) >> 7;
    const int bb = m0 >> 11;
    #pragma unroll
    for (int mi = 0; mi < 4; ++mi) {
      #pragma unroll
      for (int r = 0; r < 4; ++r) {
        const int m = m0 + wr * 64 + mi * 16 + 4 * g + r;
        const int s = m & 2047;
        const int sp = s & 1, s2 = s >> 1;
        const size_t base = ((((size_t)bb * 16 + h) * 2 + sp) << 17);  // *131072
        #pragma unroll
        for (int ni = 0; ni < 4; ++ni) {
          const int d = wc * 64 + ni * 16 + l15;
          const __bf16 v = (__bf16)acc[mi][ni][r];
          if (t == 0)      Oq[base + (size_t)s2 * 128 + d] = v;
          else if (t == 1) Ok[base + (size_t)s2 * 128 + d] = v;
          else             Ov[base + (size_t)d * 1024 + s2] = v;
        }
      }
    }
  } else {
    #pragma unroll
    for (int mi = 0; mi < 4; ++mi)
      #pragma unroll
      for (int ni = 0; ni < 4; ++ni)
        #pragma unroll
        for (int r = 0; r < 4; ++r) {
          const int m = m0 + wr * 64 + mi * 16 + 4 * g + r;
          const int n = n0 + wc * 64 + ni * 16 + l15;
          Of[(size_t)m * N + n] = acc[mi][ni][r];
        }
  }
}

// ---------------- fused dilated ring attention v4 (parity-packed) ----------------
// m97-structure: BOTH K and V LDS-staged via global_load_lds w16, single-buffer,
// 2-barrier phases. 1024 blocks = (b2,h16,p2,qt16), XCD-chunked. 4 waves, each
// owns 16 q-rows x FULL 256-col chunk -> softmax entirely in-wave (no cross-wave
// combine, no softmax LDS/barriers). acc = s[16](64) + num[8](32) = 96 AGPR;
// (256,2) gives 256-reg unified budget -> no spill (round-4 lesson).
// XOR swizzle on both tiles via pre-swizzled GLOBAL source (round-3-proven).
__global__ __launch_bounds__(256, 2) void k_attn(
    const __bf16* __restrict__ Qp, const __bf16* __restrict__ Kp,
    const __bf16* __restrict__ Vt, __bf16* __restrict__ attn) {
  __shared__ __bf16 Ks[64 * 128];   // 16 KB: 64 kv-rows x 128 d (swizzled)
  __shared__ __bf16 Vs[128 * 64];   // 16 KB: 128 d-rows x 64 kv (swizzled)
  __shared__ __bf16 E[4][16][136];  // 17 KB: wave-private halves (+8 pad)

  const int bx = blockIdx.x;
  const int wid = (bx & 7) * 128 + (bx >> 3);   // XCD-chunked (1024 % 8 == 0)
  const int qt = wid & 15, p = (wid >> 4) & 1, h = (wid >> 5) & 15, b = wid >> 9;
  const int tid = threadIdx.x;
  const int w = tid >> 6, l = tid & 63, g = l >> 4, l15 = l & 15;
  const size_t base = ((((size_t)b * 16 + h) * 2 + p) << 17);  // *131072
  const __bf16* Qb = Qp + base;
  const __bf16* Kb = Kp + base;
  const __bf16* Vb = Vt + base;
  const int q0 = qt * 64 + w * 16;
  const float SC = 1.4426950408889634f / 11.313708498984761f;  // log2(e)/sqrt(128)

  bf16x8 qf[4];
  #pragma unroll
  for (int ks = 0; ks < 4; ++ks)
    qf[ks] = *reinterpret_cast<const bf16x8*>(Qb + (size_t)(q0 + l15) * 128 + ks * 32 + 8 * g);

  f32x4 num[8] = {};
  float den[4] = {0.f, 0.f, 0.f, 0.f};

  // K staging geometry (proven round 3): chunk=1KB=4 rows of 256B.
  const int krow_in = l >> 4;                       // 0..3 within chunk
  // V staging geometry: chunk=1KB=8 rows of 128B.
  const int vrow_in = l >> 3;                       // 0..7 within chunk
  const int vsrc_e = (((l & 7) * 16) ^ (vrow_in << 4)) >> 1;  // swizzled src elem

  for (int c = 0; c < 4; ++c) {
    // ---- QK^T: 4 staged K subtiles of 64 rows ----
    f32x4 s[16] = {};
    #pragma unroll
    for (int st = 0; st < 4; ++st) {
      __syncthreads();
      #pragma unroll
      for (int i = 0; i < 4; ++i) {
        const int ch = w * 4 + i;
        const int row = ch * 4 + krow_in;          // 0..63
        const int cb = (l15 * 16) ^ ((row & 7) << 4);
        const __bf16* src = Kb + (size_t)(c * 256 + st * 64 + row) * 128 + (cb >> 1);
        __builtin_amdgcn_global_load_lds((const AS1 uint32_t*)src,
                                         (AS3 uint32_t*)(Ks + ch * 512), 16, 0, 0);
      }
      __syncthreads();
      #pragma unroll
      for (int ks = 0; ks < 4; ++ks) {
        #pragma unroll
        for (int nf2 = 0; nf2 < 4; ++nf2) {
          const int r = nf2 * 16 + l15;
          const int cb = (ks * 64 + g * 16) ^ ((r & 7) << 4);
          const bf16x8 kf = *reinterpret_cast<const bf16x8*>(Ks + r * 128 + (cb >> 1));
          s[st * 4 + nf2] = __builtin_amdgcn_mfma_f32_16x16x32_bf16(qf[ks], kf, s[st * 4 + nf2], 0, 0, 0);
        }
      }
    }
    // ---- per-chunk softmax, fully in-wave ----
    float mv[4];
    #pragma unroll
    for (int r = 0; r < 4; ++r) {
      float m0v = s[0][r];
      #pragma unroll
      for (int nf = 1; nf < 16; ++nf) m0v = fmaxf(m0v, s[nf][r]);
      m0v = fmaxf(m0v, __shfl_xor(m0v, 1));
      m0v = fmaxf(m0v, __shfl_xor(m0v, 2));
      m0v = fmaxf(m0v, __shfl_xor(m0v, 4));
      m0v = fmaxf(m0v, __shfl_xor(m0v, 8));
      mv[r] = m0v;
    }
    #pragma unroll
    for (int r = 0; r < 4; ++r) {
      float ds = 0.f;
      #pragma unroll
      for (int nf = 0; nf < 16; ++nf) {
        const float e = exp2f((s[nf][r] - mv[r]) * SC);
        s[nf][r] = e;
        ds += e;
      }
      den[r] += ds;   // per-lane partial; butterfly at epilogue (linear)
    }
    // ---- PV in two 128-col halves: E (wave-private) + 2 staged V steps ----
    #pragma unroll
    for (int h2 = 0; h2 < 2; ++h2) {
      #pragma unroll
      for (int nf = 0; nf < 8; ++nf)
        #pragma unroll
        for (int r = 0; r < 4; ++r)
          E[w][4 * g + r][nf * 16 + l15] = (__bf16)s[h2 * 8 + nf][r];
      #pragma unroll
      for (int sv = 0; sv < 2; ++sv) {
        const int kv0 = c * 256 + h2 * 128 + sv * 64;
        __syncthreads();
        #pragma unroll
        for (int i = 0; i < 4; ++i) {
          const int ch = w * 4 + i;
          const int row = ch * 8 + vrow_in;        // d-row 0..127
          const __bf16* src = Vb + (size_t)row * 1024 + kv0 + vsrc_e;
          __builtin_amdgcn_global_load_lds((const AS1 uint32_t*)src,
                                           (AS3 uint32_t*)(Vs + ch * 512), 16, 0, 0);
        }
        __syncthreads();
        #pragma unroll
        for (int ks2 = 0; ks2 < 2; ++ks2) {
          const bf16x8 a = *reinterpret_cast<const bf16x8*>(
              &E[w][l15][sv * 64 + ks2 * 32 + 8 * g]);
          #pragma unroll
          for (int nd = 0; nd < 8; ++nd) {
            const int d = nd * 16 + l15;
            const int cb = (ks2 * 64 + g * 16) ^ ((d & 7) << 4);
            const bf16x8 vf = *reinterpret_cast<const bf16x8*>(Vs + d * 64 + (cb >> 1));
            num[nd] = __builtin_amdgcn_mfma_f32_16x16x32_bf16(a, vf, num[nd], 0, 0, 0);
          }
        }
      }
    }
  }

  // ---- cross-lane den reduction (deferred) ----
  #pragma unroll
  for (int r = 0; r < 4; ++r) {
    den[r] += __shfl_xor(den[r], 1);
    den[r] += __shfl_xor(den[r], 2);
    den[r] += __shfl_xor(den[r], 4);
    den[r] += __shfl_xor(den[r], 8);
    den[r] += 1e-8f;
  }

  // ---- epilogue: out[b, 2*s'+p, h*128+d] = num/den (each wave owns its rows) ----
  #pragma unroll
  for (int nd = 0; nd < 8; ++nd)
    #pragma unroll
    for (int r = 0; r < 4; ++r) {
      const int sq = q0 + 4 * g + r;          // packed q index
      const int srow = 2 * sq + p;            // original sequence pos
      attn[((size_t)b * 2048 + srow) * 2048 + h * 128 + nd * 16 + l15] =
          (__bf16)(num[nd][r] / den[r]);
    }
}

extern "C" void kernel_launch(void* const* d_in, const int* in_sizes, int n_in,
                              void* d_out, int out_size, void* d_ws, size_t ws_size,
                              hipStream_t stream) {
  (void)in_sizes; (void)n_in; (void)out_size; (void)ws_size;
  const float* x    = (const float*)d_in[0];
  const float* wqkv = (const float*)d_in[1];
  const float* wout = (const float*)d_in[2];
  float* out = (float*)d_out;
  uint8_t* ws = (uint8_t*)d_ws;

  // workspace layout (bytes); total needed = 96 MB
  __bf16* xbf   = (__bf16*)(ws + 0);                    // 16 MB [4096][2048]
  __bf16* wqkvt = (__bf16*)(ws + (16ull << 20));        // 24 MB [6144][2048]
  __bf16* woutt = (__bf16*)(ws + (40ull << 20));        //  8 MB [2048][2048]
  __bf16* Qp    = (__bf16*)(ws + (48ull << 20));        // 16 MB [b][h][p][1024][128]
  __bf16* Kp    = (__bf16*)(ws + (64ull << 20));        // 16 MB [b][h][p][1024][128]
  __bf16* Vt    = (__bf16*)(ws + (80ull << 20));        // 16 MB [b][h][p][128][1024]
  __bf16* attn  = (__bf16*)(ws + 0);                    // reuse xbf (dead after GEMM1)

  k_cvt_x<<<8192, 256, 0, stream>>>(x, xbf);
  k_cvt_wt<<<dim3(32, 96), 256, 0, stream>>>(wqkv, wqkvt, 2048, 6144);
  k_cvt_wt<<<dim3(32, 32), 256, 0, stream>>>(wout, woutt, 2048, 2048);
  // qkv projection, fused parity-pack + V-transpose epilogue
  k_gemm_bt<1><<<dim3(48, 32), 256, 0, stream>>>(xbf, wqkvt, Qp, Kp, Vt, nullptr, 4096, 6144, 2048);
  // fused dilated attention
  k_attn<<<1024, 256, 0, stream>>>(Qp, Kp, Vt, attn);
  // output projection -> f32
  k_gemm_bt<2><<<dim3(16, 32), 256, 0, stream>>>(attn, woutt, nullptr, nullptr, nullptr, out, 4096, 2048, 2048);
}

// Round 8
// 285.797 us; speedup vs baseline: 1.5626x; 1.0393x over previous
//
#include <hip/hip_runtime.h>
#include <stdint.h>

typedef float  f32x4  __attribute__((ext_vector_type(4)));
typedef __bf16 bf16x8 __attribute__((ext_vector_type(8)));

#define AS1 __attribute__((address_space(1)))
#define AS3 __attribute__((address_space(3)))

// Problem constants
// B=2, S=2048, HID=2048, NH=16, HD=128, RING=4, CH=512, DIL=2
// packed length per (b,h,parity) = 1024; packed kv-chunk = 256

// ---- convert x -> BLOCKED bf16 A for GEMM1 ----
// blocked: elem(m,k) at ((k>>5)*32 + (m>>7))*4096 + ((k>>3)&3)*1024 + (m&127)*8 + (k&7)
// dest-coalesced mapping: d = ((kt*32+mb)*512) + kg*128 + row, thread d writes 16B.
__global__ void k_cvt_x_blk(const float* __restrict__ x, __bf16* __restrict__ y) {
  const int d = blockIdx.x * 256 + threadIdx.x;
  const int row = d & 127, kg = (d >> 7) & 3, mbkt = d >> 9;
  const int mb = mbkt & 31, kt = mbkt >> 5;
  const int m = mb * 128 + row, k0 = kt * 32 + kg * 8;
  const float4 v0 = *reinterpret_cast<const float4*>(x + (size_t)m * 2048 + k0);
  const float4 v1 = *reinterpret_cast<const float4*>(x + (size_t)m * 2048 + k0 + 4);
  bf16x8 o;
  o[0] = (__bf16)v0.x; o[1] = (__bf16)v0.y; o[2] = (__bf16)v0.z; o[3] = (__bf16)v0.w;
  o[4] = (__bf16)v1.x; o[5] = (__bf16)v1.y; o[6] = (__bf16)v1.z; o[7] = (__bf16)v1.w;
  *reinterpret_cast<bf16x8*>(y + (size_t)d * 8) = o;
}

// ------- transpose+convert W[K][N] f32 -> Wt[N][K] bf16 row-major (GEMM2's B) -------
__global__ void k_cvt_wt(const float* __restrict__ w, __bf16* __restrict__ wt,
                         const int K, const int N) {
  __shared__ float tile[64][65];
  const int k0 = blockIdx.x * 64, n0 = blockIdx.y * 64;
  const int t = threadIdx.x;
  #pragma unroll
  for (int i = 0; i < 16; ++i) {
    const int idx = t + 256 * i;
    const int r = idx >> 6, c = idx & 63;
    tile[r][c] = w[(size_t)(k0 + r) * N + n0 + c];
  }
  __syncthreads();
  #pragma unroll
  for (int i = 0; i < 16; ++i) {
    const int idx = t + 256 * i;
    const int r = idx >> 6, c = idx & 63;
    wt[(size_t)(n0 + r) * K + k0 + c] = (__bf16)tile[c][r];
  }
}

// ------- transpose+convert W[K][N] f32 -> BLOCKED bf16 B (GEMM1) -------
// blocked: elem(n,k) at ((k>>5)*NBK + (n>>7))*4096 + ((k>>3)&3)*1024 + (n&127)*8 + (k&7)
__global__ void k_cvt_wt_blk(const float* __restrict__ w, __bf16* __restrict__ wt,
                             const int N, const int NBK) {
  __shared__ float tile[64][65];
  const int k0 = blockIdx.x * 64, n0 = blockIdx.y * 64;
  const int t = threadIdx.x;
  #pragma unroll
  for (int i = 0; i < 16; ++i) {
    const int idx = t + 256 * i;
    const int r = idx >> 6, c = idx & 63;   // r = k-off, c = n-off
    tile[r][c] = w[(size_t)(k0 + r) * N + n0 + c];
  }
  __syncthreads();
  #pragma unroll
  for (int i = 0; i < 16; ++i) {
    const int idx = t + 256 * i;
    const int nn = idx >> 6, kk = idx & 63;  // kk fastest -> contiguous 8-elem runs
    const int n = n0 + nn, k = k0 + kk;
    const size_t dst = ((size_t)(k >> 5) * NBK + (n >> 7)) * 4096 +
                       (size_t)((k >> 3) & 3) * 1024 + (n & 127) * 8 + (k & 7);
    wt[dst] = (__bf16)tile[kk][nn];
  }
}

// ---------------- GEMM1 (pipelined): C = A * B^T from BLOCKED operands ----------------
// M=4096 N=6144 K=2048, 128x128 tile, BK=32, 1536 blocks (3/CU, exactly 2 rounds).
// Triple-buffered LDS, prefetch distance 2, counted s_waitcnt vmcnt(4) (never 0 in
// steady state), raw s_barrier (1/iter), setprio around MFMA, sched_barrier pin.
// Blocked layout => staging is an identity copy (coalesced gload_lds) and fragment
// ds_read_b128 are conflict-free; no swizzle needed.
// Epilogue: scatter into parity-packed Q,K (s-major) and V (d-major).
__global__ __launch_bounds__(256, 3) void k_gemm1p(
    const __bf16* __restrict__ Ab, const __bf16* __restrict__ Bb,
    __bf16* __restrict__ Oq, __bf16* __restrict__ Ok, __bf16* __restrict__ Ov) {
  __shared__ __bf16 As[3][4096];
  __shared__ __bf16 Bs[3][4096];
  const int tid = threadIdx.x;
  const int w = tid >> 6, l = tid & 63, g = l >> 4, l15 = l & 15;
  const int wr = w >> 1, wc = w & 1;
  // XCD-chunked: 1536 % 8 == 0; chunk of 192 = 4 mb-rows x 48 nb (A 2MB L2-resident)
  const int bx = blockIdx.x;
  const int wid = (bx & 7) * 192 + (bx >> 3);
  const int nb = wid % 48, mb = wid / 48;
  const size_t Abase = (size_t)mb * 4096, Bbase = (size_t)nb * 4096;
  const size_t Astep = 32 * 4096, Bstep = 48 * 4096;
  const int soff = w * 1024;           // this wave's 2-chunk staging segment (elems)

  f32x4 acc[4][4] = {};

  auto STAGE = [&](int t, int b) {
    const __bf16* as_ = Ab + (size_t)t * Astep + Abase + soff + l * 8;
    const __bf16* bs_ = Bb + (size_t)t * Bstep + Bbase + soff + l * 8;
    __builtin_amdgcn_global_load_lds((const AS1 uint32_t*)as_,
                                     (AS3 uint32_t*)(&As[b][soff]), 16, 0, 0);
    __builtin_amdgcn_global_load_lds((const AS1 uint32_t*)(as_ + 512),
                                     (AS3 uint32_t*)(&As[b][soff + 512]), 16, 0, 0);
    __builtin_amdgcn_global_load_lds((const AS1 uint32_t*)bs_,
                                     (AS3 uint32_t*)(&Bs[b][soff]), 16, 0, 0);
    __builtin_amdgcn_global_load_lds((const AS1 uint32_t*)(bs_ + 512),
                                     (AS3 uint32_t*)(&Bs[b][soff + 512]), 16, 0, 0);
  };

  // prologue: tiles 0,1 in flight; wait only tile 0 (keep tile 1 flying)
  STAGE(0, 0);
  STAGE(1, 1);
  asm volatile("s_waitcnt vmcnt(4)" ::: "memory");
  __builtin_amdgcn_s_barrier();

  int cur = 0;
  for (int t = 0; t < 64; ++t) {
    int b2 = cur + 2; if (b2 >= 3) b2 -= 3;
    if (t + 2 < 64) STAGE(t + 2, b2);
    // fragment reads (conflict-free: contiguous 16B per 16-lane group)
    const __bf16* Ar = &As[cur][g * 1024 + (wr * 64 + l15) * 8];
    const __bf16* Br = &Bs[cur][g * 1024 + (wc * 64 + l15) * 8];
    bf16x8 af[4], bfr[4];
    #pragma unroll
    for (int mi = 0; mi < 4; ++mi) af[mi] = *reinterpret_cast<const bf16x8*>(Ar + mi * 128);
    #pragma unroll
    for (int ni = 0; ni < 4; ++ni) bfr[ni] = *reinterpret_cast<const bf16x8*>(Br + ni * 128);
    __builtin_amdgcn_s_setprio(1);
    #pragma unroll
    for (int mi = 0; mi < 4; ++mi)
      #pragma unroll
      for (int ni = 0; ni < 4; ++ni)
        acc[mi][ni] = __builtin_amdgcn_mfma_f32_16x16x32_bf16(af[mi], bfr[ni], acc[mi][ni], 0, 0, 0);
    __builtin_amdgcn_s_setprio(0);
    __builtin_amdgcn_sched_barrier(0);
    if (t < 62) asm volatile("s_waitcnt vmcnt(4)" ::: "memory");  // retire tile t+1 only
    else        asm volatile("s_waitcnt vmcnt(0)" ::: "memory");  // tail drain
    __builtin_amdgcn_s_barrier();
    cur = cur + 1; if (cur >= 3) cur -= 3;
  }

  // ---- epilogue: scatter into parity-packed Q,K and d-major V ----
  const int m0 = mb * 128, n0 = nb * 128;
  const int ty = n0 >> 11;                // 0:q 1:k 2:v
  const int h = (n0 & 2047) >> 7;
  #pragma unroll
  for (int mi = 0; mi < 4; ++mi) {
    #pragma unroll
    for (int r = 0; r < 4; ++r) {
      const int m = m0 + wr * 64 + mi * 16 + 4 * g + r;
      const int s = m & 2047;
      const int sp = s & 1, s2 = s >> 1;
      const int bb = m >> 11;
      const size_t base = ((((size_t)bb * 16 + h) * 2 + sp) << 17);  // *131072
      #pragma unroll
      for (int ni = 0; ni < 4; ++ni) {
        const int d = wc * 64 + ni * 16 + l15;
        const __bf16 v = (__bf16)acc[mi][ni][r];
        if (ty == 0)      Oq[base + (size_t)s2 * 128 + d] = v;
        else if (ty == 1) Ok[base + (size_t)s2 * 128 + d] = v;
        else              Ov[base + (size_t)d * 1024 + s2] = v;
      }
    }
  }
}

// ---------------- bt-GEMM (m97-style) for the output projection ----------------
__global__ __launch_bounds__(256, 2) void k_gemm_bt2(
    const __bf16* __restrict__ A, const __bf16* __restrict__ Bt,
    float* __restrict__ Of, const int M, const int N, const int K) {
  __shared__ __bf16 As[128 * 32];
  __shared__ __bf16 Bs[128 * 32];
  const int tid = threadIdx.x;
  const int w = tid >> 6, l = tid & 63, g = l >> 4, l15 = l & 15;
  const int wr = w >> 1, wc = w & 1;
  const int m0 = blockIdx.y * 128, n0 = blockIdx.x * 128;
  const int srow = l >> 2, scol = (l & 3) * 8;

  f32x4 acc[4][4] = {};

  for (int kt = 0; kt < K; kt += 32) {
    __syncthreads();
    #pragma unroll
    for (int i = 0; i < 2; ++i) {
      const int ch = w * 2 + i;
      const int row = ch * 16 + srow;
      __builtin_amdgcn_global_load_lds(
          (const AS1 uint32_t*)(A + (size_t)(m0 + row) * K + kt + scol),
          (AS3 uint32_t*)(As + ch * 512), 16, 0, 0);
      __builtin_amdgcn_global_load_lds(
          (const AS1 uint32_t*)(Bt + (size_t)(n0 + row) * K + kt + scol),
          (AS3 uint32_t*)(Bs + ch * 512), 16, 0, 0);
    }
    __syncthreads();

    bf16x8 af[4], bfr[4];
    #pragma unroll
    for (int mi = 0; mi < 4; ++mi)
      af[mi] = *reinterpret_cast<const bf16x8*>(As + (wr * 64 + mi * 16 + l15) * 32 + 8 * g);
    #pragma unroll
    for (int ni = 0; ni < 4; ++ni)
      bfr[ni] = *reinterpret_cast<const bf16x8*>(Bs + (wc * 64 + ni * 16 + l15) * 32 + 8 * g);
    #pragma unroll
    for (int mi = 0; mi < 4; ++mi)
      #pragma unroll
      for (int ni = 0; ni < 4; ++ni)
        acc[mi][ni] = __builtin_amdgcn_mfma_f32_16x16x32_bf16(af[mi], bfr[ni], acc[mi][ni], 0, 0, 0);
  }

  #pragma unroll
  for (int mi = 0; mi < 4; ++mi)
    #pragma unroll
    for (int ni = 0; ni < 4; ++ni)
      #pragma unroll
      for (int r = 0; r < 4; ++r) {
        const int m = m0 + wr * 64 + mi * 16 + 4 * g + r;
        const int n = n0 + wc * 64 + ni * 16 + l15;
        Of[(size_t)m * N + n] = acc[mi][ni][r];
      }
}

// ---------------- fused dilated ring attention v4 (unchanged from round 7) ----------------
__global__ __launch_bounds__(256, 2) void k_attn(
    const __bf16* __restrict__ Qp, const __bf16* __restrict__ Kp,
    const __bf16* __restrict__ Vt, __bf16* __restrict__ attn) {
  __shared__ __bf16 Ks[64 * 128];
  __shared__ __bf16 Vs[128 * 64];
  __shared__ __bf16 E[4][16][136];

  const int bx = blockIdx.x;
  const int wid = (bx & 7) * 128 + (bx >> 3);
  const int qt = wid & 15, p = (wid >> 4) & 1, h = (wid >> 5) & 15, b = wid >> 9;
  const int tid = threadIdx.x;
  const int w = tid >> 6, l = tid & 63, g = l >> 4, l15 = l & 15;
  const size_t base = ((((size_t)b * 16 + h) * 2 + p) << 17);
  const __bf16* Qb = Qp + base;
  const __bf16* Kb = Kp + base;
  const __bf16* Vb = Vt + base;
  const int q0 = qt * 64 + w * 16;
  const float SC = 1.4426950408889634f / 11.313708498984761f;

  bf16x8 qf[4];
  #pragma unroll
  for (int ks = 0; ks < 4; ++ks)
    qf[ks] = *reinterpret_cast<const bf16x8*>(Qb + (size_t)(q0 + l15) * 128 + ks * 32 + 8 * g);

  f32x4 num[8] = {};
  float den[4] = {0.f, 0.f, 0.f, 0.f};

  const int krow_in = l >> 4;
  const int vrow_in = l >> 3;
  const int vsrc_e = (((l & 7) * 16) ^ (vrow_in << 4)) >> 1;

  for (int c = 0; c < 4; ++c) {
    f32x4 s[16] = {};
    #pragma unroll
    for (int st = 0; st < 4; ++st) {
      __syncthreads();
      #pragma unroll
      for (int i = 0; i < 4; ++i) {
        const int ch = w * 4 + i;
        const int row = ch * 4 + krow_in;
        const int cb = (l15 * 16) ^ ((row & 7) << 4);
        const __bf16* src = Kb + (size_t)(c * 256 + st * 64 + row) * 128 + (cb >> 1);
        __builtin_amdgcn_global_load_lds((const AS1 uint32_t*)src,
                                         (AS3 uint32_t*)(Ks + ch * 512), 16, 0, 0);
      }
      __syncthreads();
      #pragma unroll
      for (int ks = 0; ks < 4; ++ks) {
        #pragma unroll
        for (int nf2 = 0; nf2 < 4; ++nf2) {
          const int r = nf2 * 16 + l15;
          const int cb = (ks * 64 + g * 16) ^ ((r & 7) << 4);
          const bf16x8 kf = *reinterpret_cast<const bf16x8*>(Ks + r * 128 + (cb >> 1));
          s[st * 4 + nf2] = __builtin_amdgcn_mfma_f32_16x16x32_bf16(qf[ks], kf, s[st * 4 + nf2], 0, 0, 0);
        }
      }
    }
    float mv[4];
    #pragma unroll
    for (int r = 0; r < 4; ++r) {
      float m0v = s[0][r];
      #pragma unroll
      for (int nf = 1; nf < 16; ++nf) m0v = fmaxf(m0v, s[nf][r]);
      m0v = fmaxf(m0v, __shfl_xor(m0v, 1));
      m0v = fmaxf(m0v, __shfl_xor(m0v, 2));
      m0v = fmaxf(m0v, __shfl_xor(m0v, 4));
      m0v = fmaxf(m0v, __shfl_xor(m0v, 8));
      mv[r] = m0v;
    }
    #pragma unroll
    for (int r = 0; r < 4; ++r) {
      float ds = 0.f;
      #pragma unroll
      for (int nf = 0; nf < 16; ++nf) {
        const float e = exp2f((s[nf][r] - mv[r]) * SC);
        s[nf][r] = e;
        ds += e;
      }
      den[r] += ds;
    }
    #pragma unroll
    for (int h2 = 0; h2 < 2; ++h2) {
      #pragma unroll
      for (int nf = 0; nf < 8; ++nf)
        #pragma unroll
        for (int r = 0; r < 4; ++r)
          E[w][4 * g + r][nf * 16 + l15] = (__bf16)s[h2 * 8 + nf][r];
      #pragma unroll
      for (int sv = 0; sv < 2; ++sv) {
        const int kv0 = c * 256 + h2 * 128 + sv * 64;
        __syncthreads();
        #pragma unroll
        for (int i = 0; i < 4; ++i) {
          const int ch = w * 4 + i;
          const int row = ch * 8 + vrow_in;
          const __bf16* src = Vb + (size_t)row * 1024 + kv0 + vsrc_e;
          __builtin_amdgcn_global_load_lds((const AS1 uint32_t*)src,
                                           (AS3 uint32_t*)(Vs + ch * 512), 16, 0, 0);
        }
        __syncthreads();
        #pragma unroll
        for (int ks2 = 0; ks2 < 2; ++ks2) {
          const bf16x8 a = *reinterpret_cast<const bf16x8*>(
              &E[w][l15][sv * 64 + ks2 * 32 + 8 * g]);
          #pragma unroll
          for (int nd = 0; nd < 8; ++nd) {
            const int d = nd * 16 + l15;
            const int cb = (ks2 * 64 + g * 16) ^ ((d & 7) << 4);
            const bf16x8 vf = *reinterpret_cast<const bf16x8*>(Vs + d * 64 + (cb >> 1));
            num[nd] = __builtin_amdgcn_mfma_f32_16x16x32_bf16(a, vf, num[nd], 0, 0, 0);
          }
        }
      }
    }
  }

  #pragma unroll
  for (int r = 0; r < 4; ++r) {
    den[r] += __shfl_xor(den[r], 1);
    den[r] += __shfl_xor(den[r], 2);
    den[r] += __shfl_xor(den[r], 4);
    den[r] += __shfl_xor(den[r], 8);
    den[r] += 1e-8f;
  }

  #pragma unroll
  for (int nd = 0; nd < 8; ++nd)
    #pragma unroll
    for (int r = 0; r < 4; ++r) {
      const int sq = q0 + 4 * g + r;
      const int srow = 2 * sq + p;
      attn[((size_t)b * 2048 + srow) * 2048 + h * 128 + nd * 16 + l15] =
          (__bf16)(num[nd][r] / den[r]);
    }
}

extern "C" void kernel_launch(void* const* d_in, const int* in_sizes, int n_in,
                              void* d_out, int out_size, void* d_ws, size_t ws_size,
                              hipStream_t stream) {
  (void)in_sizes; (void)n_in; (void)out_size; (void)ws_size;
  const float* x    = (const float*)d_in[0];
  const float* wqkv = (const float*)d_in[1];
  const float* wout = (const float*)d_in[2];
  float* out = (float*)d_out;
  uint8_t* ws = (uint8_t*)d_ws;

  // workspace layout (bytes); total needed = 96 MB
  __bf16* xbf   = (__bf16*)(ws + 0);                    // 16 MB blocked A [64][32][4096]
  __bf16* wqkvt = (__bf16*)(ws + (16ull << 20));        // 24 MB blocked B [64][48][4096]
  __bf16* woutt = (__bf16*)(ws + (40ull << 20));        //  8 MB row-major [2048][2048]
  __bf16* Qp    = (__bf16*)(ws + (48ull << 20));        // 16 MB [b][h][p][1024][128]
  __bf16* Kp    = (__bf16*)(ws + (64ull << 20));        // 16 MB [b][h][p][1024][128]
  __bf16* Vt    = (__bf16*)(ws + (80ull << 20));        // 16 MB [b][h][p][128][1024]
  __bf16* attn  = (__bf16*)(ws + 0);                    // reuse xbf (dead after GEMM1)

  k_cvt_x_blk<<<4096, 256, 0, stream>>>(x, xbf);
  k_cvt_wt_blk<<<dim3(32, 96), 256, 0, stream>>>(wqkv, wqkvt, 6144, 48);
  k_cvt_wt<<<dim3(32, 32), 256, 0, stream>>>(wout, woutt, 2048, 2048);
  // qkv projection (pipelined, blocked operands), fused parity-pack + V-transpose
  k_gemm1p<<<1536, 256, 0, stream>>>(xbf, wqkvt, Qp, Kp, Vt);
  // fused dilated attention
  k_attn<<<1024, 256, 0, stream>>>(Qp, Kp, Vt, attn);
  // output projection -> f32
  k_gemm_bt2<<<dim3(16, 32), 256, 0, stream>>>(attn, woutt, out, 4096, 2048, 2048);
}